// Round 5
// baseline (377.172 us; speedup 1.0000x reference)
//
#include <hip/hip_runtime.h>

// Stencil gather: out[b,j,k,{center,up,right,down,left}], edge-replicated.
// B=16, H=1024, W=1024, f32. 64 MiB read + 320 MiB write -> ~61 us floor.
//
// R1: direct 80B/thread stores -> 4x store-line amplification (~204 us kernel).
// R2/R3: block-wide LDS transpose + coalesced stores -> ~140 us kernel;
//        nt vs plain stores within noise (nt slightly better).
// R4: strip + wave-private LDS, NO synchronization -> WRONG (absmax 1882):
//     compiler interleaved unrolled iterations' ds_writes above prior
//     ds_reads (per-thread LDS accesses look non-aliasing; cross-lane
//     dependence is invisible). Lesson: wave-private LDS still needs a
//     compiler ordering fence.
// R5 (this): R4 structure + asm ordering fences:
//   * "s_waitcnt lgkmcnt(0)" + memory clobber between LDS write and read
//     phases (HW processes same-wave DS ops in order; the fence pins the
//     instruction order the HW guarantee applies to). Pure clobber after
//     reads stops next iteration's writes from hoisting. No s_barrier ->
//     no vmcnt(0) store drains.
//   * One block = 16-row strip; u/c/d rows rotate through registers
//     (read amplification 3x -> 1.125x, no cross-XCD re-reads).
//   * Depth-1 row prefetch (global loads are vmcnt, unaffected by the
//     lgkmcnt fence -> stay in flight across it).
//   * Bank-conflict-free by construction: phase-1 b128 writes, 8 lanes
//     cover all 32 banks exactly once; phase-2 reads lane-consecutive.

typedef float f4 __attribute__((ext_vector_type(4)));

__global__ __launch_bounds__(256) void stencil5_kernel(
    const float* __restrict__ in, float* __restrict__ out) {
    constexpr int W = 1024;
    constexpr int H = 1024;
    constexpr int R = 16;              // rows per block (strip height)

    __shared__ float lds[4 * 1280];    // 20 KiB: 5 KiB per wave, wave-private

    const int i  = threadIdx.x;        // 0..255
    const int wv = i >> 6;             // wave 0..3
    const int ln = i & 63;             // lane
    const int k0 = i << 2;             // column of this thread's 4 pixels

    const int strip = blockIdx.x;      // 1024 strips total
    const int img   = strip >> 6;      // 64 strips per image
    const int j0    = (strip & 63) << 4;   // strip start row in image

    const float* pimg = in + ((long)img << 20) + k0;
    const long   row0 = ((long)img << 10) + j0;   // global flat row index

    const int loff = (k0 > 0)     ? -1 : 0;   // clamped edge offsets
    const int roff = (k0 + 4 < W) ?  4 : 3;

    // Prologue: rows j0-1 (replicated at image top), j0, j0+1.
    const float* p0 = pimg + ((long)j0 << 10);
    float4 c = *(const float4*)p0;
    float4 u = (j0 > 0) ? *(const float4*)(p0 - W) : c;   // uniform branch
    const float* p1 = p0 + W;                              // j0+1 <= H-1 always
    float4 d = *(const float4*)p1;
    float lx  = p0[loff], rw  = p0[roff];
    float dlx = p1[loff], drw = p1[roff];

    float*    lw = lds + wv * 1280;        // this wave's LDS region
    f4*       l5 = (f4*)(lw + ln * 20);    // phase-1 target (5 float4s)
    const f4* ls = (const f4*)lw;          // phase-2 source

    for (int r = 0; r < R; ++r) {
        const int jr = j0 + r;

        // Prefetch row jr+2 (+ its edge scalars), clamped at image bottom
        // (the clamped value is never actually consumed: dd selects c).
        const int jn = jr + 2;
        const int mf = (jn < H) ? jn : H - 1;
        const float* pf = pimg + ((long)mf << 10);
        float4 f  = *(const float4*)pf;
        float flx = pf[loff], frw = pf[roff];

        // Effective neighbors with border replication.
        const float4 dd  = (jr + 1 < H) ? d : c;
        const float  lxe = (k0 > 0)     ? lx : c.x;
        const float  rwe = (k0 + 4 < W) ? rw : c.w;

        // Phase 1: intra-wave LDS transpose, 20 floats/thread, pixel-major:
        // [c.x,u.x,c.y,dd.x,lxe | c.y,u.y,c.z,dd.y,c.x |
        //  c.z,u.z,c.w,dd.z,c.y | c.w,u.w,rwe,dd.w,c.z]
        l5[0] = f4{c.x,  u.x,  c.y,  dd.x};
        l5[1] = f4{lxe,  c.y,  u.y,  c.z };
        l5[2] = f4{dd.y, c.x,  c.z,  u.z };
        l5[3] = f4{c.w,  dd.z, c.y,  c.w };
        l5[4] = f4{u.w,  rwe,  dd.w, c.z };

        // Ordering fence: drain this wave's DS writes, forbid compiler from
        // moving the reads above the writes. lgkmcnt does NOT wait on the
        // global prefetch (vmcnt), so the pipeline stays primed.
        asm volatile("s_waitcnt lgkmcnt(0)" ::: "memory");

        // Phase 2: coalesced nt stores -- wave w covers output float4s
        // [320w, 320w+320) of row jr, exactly the pixels it computed.
        f4* o4 = (f4*)(out + (row0 + r) * 5120) + wv * 320;
        #pragma unroll
        for (int q = 0; q < 5; ++q)
            __builtin_nontemporal_store(ls[ln + 64 * q], o4 + ln + 64 * q);

        // Forbid next iteration's DS writes from hoisting above these reads.
        asm volatile("" ::: "memory");

        // Rotate the row window.
        u = c; c = d; d = f;
        lx = dlx; rw = drw; dlx = flx; drw = frw;
    }
}

extern "C" void kernel_launch(void* const* d_in, const int* in_sizes, int n_in,
                              void* d_out, int out_size, void* d_ws, size_t ws_size,
                              hipStream_t stream) {
    const float* in = (const float*)d_in[0];
    float* out = (float*)d_out;

    const int n = in_sizes[0];             // 16 * 1024 * 1024
    const int blocks = (n >> 10) >> 4;     // rows / 16 = 1024 strips

    stencil5_kernel<<<blocks, 256, 0, stream>>>(in, out);
}